// Round 3
// baseline (421.760 us; speedup 1.0000x reference)
//
#include <hip/hip_runtime.h>
#include <hip/hip_bf16.h>

// CentralSpecificModel: per-species 2-layer MLP (256 -> 1024 -> 256), 4 species,
// N=65536 rows, fp32 in/out. Bucket rows by species; fused per-64-row-tile
// kernel does GEMM1+silu+GEMM2 with bf16 MFMA (16x16x32), swapped operands
// (weights as A, X/H as B -> H^T/Y^T, packed b64 Hs writes, float4 epilogue).
// R5 = R4 fused kernel + R3-verified launch structure (no hipMemsetAsync —
// suspect in the R4 container failure; prep_kernel zeroes cnt, count_fill
// second, fused third).
// Fused kernel is LATENCY-bound (R3 counters: MfmaUtil 22%, VALUBusy 21%,
// Occ 17%; all pipe floors ~33us vs 129us measured) at 2 blocks/CU. Fix:
// LDS 74752->51712 (Xs stride 280->264 = 132 dw == 4 mod 32, 2-way max on
// b128 reads; Hs single-buffered, stride 140 = 70 dw == 6 mod 32, <=2-way
// writes) -> __launch_bounds__(256,3), 3 blocks/CU, 12 waves. The extra
// drain barrier per chunk is hidden: silu results staged in regs, Hs writes
// deferred past the barrier so prior GEMM2 readers drain under GEMM1+silu.

#define N_ATOMS 65536
#define D_IN 256
#define D_HID 1024
#define D_OUT 256
#define TPS 1024   // max 64-row tiles per species (worst case: all rows one species)

typedef __attribute__((ext_vector_type(8))) short short8;
typedef __attribute__((ext_vector_type(4))) short short4v;
typedef __attribute__((ext_vector_type(4))) float float4e;

// ws layout (bytes):
//   [0, 256)           cnt[4] padded: cnt[s] at int offset s*16 (64B apart)
//   [256, 1048832)     bucket[4][65536] int
//   [1048832, 3145984) W1 swizzled bf16 fragments (4*256*1024)
//   [3145984, 5243136) W2 swizzled bf16 fragments (4*1024*256)
#define WS_BUCKET_OFF 256
#define WS_W1_OFF 1048832
#define WS_W2_OFF 3145984

__device__ __forceinline__ short f2bf(float f) {
  unsigned u = __builtin_bit_cast(unsigned, f);
  unsigned r = (u + 0x7FFFu + ((u >> 16) & 1u)) >> 16;   // round-to-nearest-even
  return (short)r;
}

// Swizzle W1/W2 fp32 -> bf16 MFMA B-fragment order; zero padded counters.
// B-frag (16x16x32): lane l holds B[k0 + 8*(l>>4) + j][nt*16 + (l&15)], j=0..7.
// (Used as the A operand in the swapped fused kernel: identical register
// content, interpreted as A[m = l&15][k] = W^T fragment.)
__global__ void prep_kernel(const float* __restrict__ W1, const float* __restrict__ W2,
                            short* __restrict__ w1sw, short* __restrict__ w2sw,
                            int* __restrict__ cnt) {
  int gid = blockIdx.x * 256 + threadIdx.x;   // 262144 threads
  if (gid < 64) cnt[gid] = 0;
  int lane = gid & 63;
  int lr = lane & 15;
  int lk = (lane >> 4) * 8;
  if (gid < 131072) {            // W1: [4][256][1024], NT=64, KS=8
    int ks = (gid >> 6) & 7;
    int nt = (gid >> 9) & 63;
    int s  = gid >> 15;
    const float* src = W1 + ((size_t)(s * 256 + ks * 32 + lk)) * 1024 + nt * 16 + lr;
    short8 v;
    for (int j = 0; j < 8; ++j) v[j] = f2bf(src[(size_t)j * 1024]);
    *(short8*)(w1sw + (size_t)gid * 8) = v;
  } else {                       // W2: [4][1024][256], NT=16, KS=32
    int g = gid - 131072;
    int kt = (g >> 6) & 31;
    int nt = (g >> 11) & 15;
    int s  = g >> 15;
    const float* src = W2 + ((size_t)(s * 1024 + kt * 32 + lk)) * 256 + nt * 16 + lr;
    short8 v;
    for (int j = 0; j < 8; ++j) v[j] = f2bf(src[(size_t)j * 256]);
    *(short8*)(w2sw + (size_t)g * 8) = v;
  }
}

// Bucket rows by species. 32 blocks x 2048 rows. Two-pass block-internal
// histogram: pass 1 computes per-(iter,wave,species) counts + per-lane ranks;
// ONE atomicAdd per species per block; pass 2 scatters. Bucket order within a
// species is irrelevant (rows are independent).
#define CF_BLOCKS 32
#define CF_ITERS 8
__global__ void count_fill_kernel(const int* __restrict__ species,
                                  int* __restrict__ cnt, int* __restrict__ bucket) {
  int tid = threadIdx.x;
  int lane = tid & 63, wid = tid >> 6;
  __shared__ int wcnt[CF_ITERS][4][4];   // [iter][wave][species]
  __shared__ int wb[CF_ITERS][4][4];     // exclusive prefix within block
  __shared__ int base_sm[4];
  int sv[CF_ITERS], rk[CF_ITERS];
  unsigned long long below = (1ull << lane) - 1ull;
  int base_i = blockIdx.x * (CF_ITERS * 256);
  #pragma unroll
  for (int it = 0; it < CF_ITERS; ++it) {
    int s = species[base_i + it * 256 + tid] & 3;
    sv[it] = s;
    unsigned long long m0 = __ballot(s == 0);
    unsigned long long m1 = __ballot(s == 1);
    unsigned long long m2 = __ballot(s == 2);
    unsigned long long m3 = __ballot(s == 3);
    unsigned long long ms = (s == 0) ? m0 : (s == 1) ? m1 : (s == 2) ? m2 : m3;
    rk[it] = __popcll(ms & below);
    if (lane == 0) {
      wcnt[it][wid][0] = __popcll(m0);
      wcnt[it][wid][1] = __popcll(m1);
      wcnt[it][wid][2] = __popcll(m2);
      wcnt[it][wid][3] = __popcll(m3);
    }
  }
  __syncthreads();
  if (tid < 4) {
    int ss = tid, run = 0;
    for (int it = 0; it < CF_ITERS; ++it)
      for (int w = 0; w < 4; ++w) {
        wb[it][w][ss] = run;
        run += wcnt[it][w][ss];
      }
    base_sm[ss] = atomicAdd(&cnt[ss * 16], run);
  }
  __syncthreads();
  #pragma unroll
  for (int it = 0; it < CF_ITERS; ++it) {
    int ss = sv[it];
    bucket[ss * N_ATOMS + base_sm[ss] + wb[it][wid][ss] + rk[it]] = base_i + it * 256 + tid;
  }
}

// Fused per-tile MLP, swapped-operand form. Block = 256 threads (4 waves),
// tile = 64 rows. GEMM1: H^T = W1^T @ X^T, lane holds 4 consecutive hid ->
// packed b64 Hs writes. GEMM2: Y^T = W2^T @ H^T -> float4 epilogue stores.
// LDS 51712B (Xs 64x264 + single-buffered Hs 64x140) -> 3 blocks/CU.
#define XS_STRIDE 264
#define HS_STRIDE 140
__global__ __launch_bounds__(256, 3) void fused_kernel(
    const float* __restrict__ x, const int* __restrict__ cntArr,
    const int* __restrict__ bucket, const short* __restrict__ w1sw,
    const short* __restrict__ w2sw, const float* __restrict__ b1,
    const float* __restrict__ b2, float* __restrict__ out) {
  int bid = blockIdx.x;
  // XCD swizzle: bid%8 round-robins XCDs; give species s to XCD pair {2s,2s+1}
  // so each XCD L2 only holds ~1MB of weight fragments.
  int s = (bid & 7) >> 1;
  int t = ((bid >> 3) << 1) | (bid & 1);
  int cnt = cntArr[s * 16];
  int r0 = t * 64;
  if (r0 >= cnt) return;
  int nrows = min(64, cnt - r0);
  const int* buck = bucket + s * N_ATOMS + r0;

  __shared__ short Xs[64 * XS_STRIDE];   // 33792 B
  __shared__ short Hs[64 * HS_STRIDE];   // 17920 B

  int tid = threadIdx.x;

  // Stage gathered x tile -> bf16 LDS. 2048 8-elem groups / 256 threads.
  for (int i = 0; i < 8; ++i) {
    int id = tid + i * 256;
    int r = id >> 5;          // row 0..63
    int g = id & 31;          // 8-float group
    short8 v = {};
    if (r < nrows) {
      const float4* src = (const float4*)(x + (size_t)buck[r] * D_IN + g * 8);
      float4 f0 = src[0];
      float4 f1 = src[1];
      v[0] = f2bf(f0.x); v[1] = f2bf(f0.y); v[2] = f2bf(f0.z); v[3] = f2bf(f0.w);
      v[4] = f2bf(f1.x); v[5] = f2bf(f1.y); v[6] = f2bf(f1.z); v[7] = f2bf(f1.w);
    }
    *(short8*)(Xs + r * XS_STRIDE + g * 8) = v;
  }

  int lane = tid & 63;
  int wid = tid >> 6;
  int lr = lane & 15;          // row within 16-tile (X-row in swapped form)
  int lk = (lane >> 4) * 8;    // k base within 32-kstep
  int lq = (lane >> 4) * 4;    // hid/out base within 16-tile

  // Row gather indices for the epilogue (per bt tile).
  int rowIdx[4];
  #pragma unroll
  for (int bt = 0; bt < 4; ++bt) {
    int r = bt * 16 + lr;
    rowIdx[bt] = (r < nrows) ? buck[r] : -1;
  }

  // accY init = b2 bias (folded; saves epilogue adds).
  float4e accY[4][4];
  #pragma unroll
  for (int at = 0; at < 4; ++at) {
    float4e bv = *(const float4e*)(b2 + s * D_OUT + wid * 64 + at * 16 + lq);
    #pragma unroll
    for (int bt = 0; bt < 4; ++bt) accY[at][bt] = bv;
  }

  // Preload GEMM1 W1-fragments for c=0 (16 batched loads).
  short8 b1f[16];
  #pragma unroll
  for (int ks = 0; ks < 8; ++ks)
    #pragma unroll
    for (int at = 0; at < 2; ++at) {
      int nt = 0 * 8 + wid * 2 + at;
      b1f[ks * 2 + at] = *(const short8*)(w1sw + ((size_t)((s * 64 + nt) * 8 + ks)) * 512 + lane * 8);
    }

  __syncthreads();   // Xs ready

  for (int c = 0; c < 8; ++c) {
    // acc1 init = b1 bias for this chunk's hid slice.
    float4e acc1[2][4];
    #pragma unroll
    for (int at = 0; at < 2; ++at) {
      float4e bv = *(const float4e*)(b1 + s * D_HID + c * 128 + wid * 32 + at * 16 + lq);
      #pragma unroll
      for (int bt = 0; bt < 4; ++bt) acc1[at][bt] = bv;
    }
    // ---- GEMM1: H^T chunk [128 hid x 64 rows] = W1^T @ X^T ----
    #pragma unroll
    for (int ks = 0; ks < 8; ++ks) {
      short8 xb[4];
      #pragma unroll
      for (int bt = 0; bt < 4; ++bt)
        xb[bt] = *(const short8*)(Xs + (bt * 16 + lr) * XS_STRIDE + ks * 32 + lk);
      #pragma unroll
      for (int at = 0; at < 2; ++at)
        #pragma unroll
        for (int bt = 0; bt < 4; ++bt)
          acc1[at][bt] = __builtin_amdgcn_mfma_f32_16x16x32_bf16(b1f[ks * 2 + at], xb[bt], acc1[at][bt], 0, 0, 0);
    }
    // ---- prefetch GEMM2 W2-fragments (L2 latency hidden under silu) ----
    short8 b2f[16];
    #pragma unroll
    for (int ks = 0; ks < 4; ++ks)
      #pragma unroll
      for (int at = 0; at < 4; ++at) {
        int nt = wid * 4 + at;
        int kt = c * 4 + ks;
        b2f[ks * 4 + at] = *(const short8*)(w2sw + ((size_t)((s * 16 + nt) * 32 + kt)) * 512 + lane * 8);
      }
    // ---- silu into REGISTERS (writes deferred past the drain barrier) ----
    short4v hv[2][4];
    #pragma unroll
    for (int at = 0; at < 2; ++at)
      #pragma unroll
      for (int bt = 0; bt < 4; ++bt) {
        float4e v4 = acc1[at][bt];
        short4v h;
        #pragma unroll
        for (int q = 0; q < 4; ++q) {
          float pre = v4[q];
          float val = pre * __builtin_amdgcn_rcpf(1.0f + __expf(-pre));  // silu
          h[q] = f2bf(val);
        }
        hv[at][bt] = h;
      }
    __syncthreads();   // prior chunk's GEMM2 readers of Hs are done
    // ---- Hs writes (packed b64: 4 consecutive hid per lane) ----
    #pragma unroll
    for (int at = 0; at < 2; ++at) {
      int hidloc = wid * 32 + at * 16 + lq;
      #pragma unroll
      for (int bt = 0; bt < 4; ++bt)
        *(short4v*)(Hs + (bt * 16 + lr) * HS_STRIDE + hidloc) = hv[at][bt];
    }
    __syncthreads();   // Hs chunk c visible to all waves
    // ---- prefetch next chunk's W1-fragments (hidden under GEMM2 MFMA) ----
    if (c < 7) {
      #pragma unroll
      for (int ks = 0; ks < 8; ++ks)
        #pragma unroll
        for (int at = 0; at < 2; ++at) {
          int nt = (c + 1) * 8 + wid * 2 + at;
          b1f[ks * 2 + at] = *(const short8*)(w1sw + ((size_t)((s * 64 + nt) * 8 + ks)) * 512 + lane * 8);
        }
    }
    // ---- GEMM2 partial: Y^T += W2^T @ H^T ----
    #pragma unroll
    for (int ks = 0; ks < 4; ++ks) {
      short8 hb[4];
      #pragma unroll
      for (int bt = 0; bt < 4; ++bt)
        hb[bt] = *(const short8*)(Hs + (bt * 16 + lr) * HS_STRIDE + ks * 32 + lk);
      #pragma unroll
      for (int at = 0; at < 4; ++at)
        #pragma unroll
        for (int bt = 0; bt < 4; ++bt)
          accY[at][bt] = __builtin_amdgcn_mfma_f32_16x16x32_bf16(b2f[ks * 4 + at], hb[bt], accY[at][bt], 0, 0, 0);
    }
  }

  // ---- epilogue: scatter Y rows, 16B per lane (bias already folded in) ----
  #pragma unroll
  for (int at = 0; at < 4; ++at) {
    int nb = wid * 64 + at * 16 + lq;
    #pragma unroll
    for (int bt = 0; bt < 4; ++bt) {
      if (rowIdx[bt] >= 0)
        *(float4e*)(out + (size_t)rowIdx[bt] * D_OUT + nb) = accY[at][bt];
    }
  }
}

extern "C" void kernel_launch(void* const* d_in, const int* in_sizes, int n_in,
                              void* d_out, int out_size, void* d_ws, size_t ws_size,
                              hipStream_t stream) {
  const float* x  = (const float*)d_in[0];
  const int* spc  = (const int*)d_in[1];
  const float* W1 = (const float*)d_in[2];
  const float* b1 = (const float*)d_in[3];
  const float* W2 = (const float*)d_in[4];
  const float* b2 = (const float*)d_in[5];
  float* out = (float*)d_out;

  int*   cnt    = (int*)d_ws;
  int*   bucket = (int*)((char*)d_ws + WS_BUCKET_OFF);
  short* w1sw   = (short*)((char*)d_ws + WS_W1_OFF);
  short* w2sw   = (short*)((char*)d_ws + WS_W2_OFF);

  prep_kernel<<<1024, 256, 0, stream>>>(W1, W2, w1sw, w2sw, cnt);
  count_fill_kernel<<<CF_BLOCKS, 256, 0, stream>>>(spc, cnt, bucket);
  fused_kernel<<<4 * TPS, 256, 0, stream>>>(x, cnt, bucket, w1sw, w2sw, b1, b2, out);
}

// Round 4
// 315.946 us; speedup vs baseline: 1.3349x; 1.3349x over previous
//
#include <hip/hip_runtime.h>
#include <hip/hip_bf16.h>

// CentralSpecificModel: per-species 2-layer MLP (256 -> 1024 -> 256), 4 species,
// N=65536 rows, fp32 in/out. Bucket rows by species; fused per-64-row-tile
// kernel does GEMM1+silu+GEMM2 with bf16 MFMA (16x16x32), swapped operands
// (weights as A, X/H as B -> H^T/Y^T, packed b64 Hs writes, float4 epilogue).
// R6: R5's launch_bounds(256,3) reg-cap (~170 unified) forced ~660MB of scratch
// spills (VGPR 128->84, hbm_bytes 0.11->1.07GB, 322us). Occupancy must come
// from THINNER PER-WAVE TILES, not LDS squeezing: 8 waves/block (512 thr),
// same 64-row tile. Per wave: GEMM1 owns 16 hid cols (b1f 32 regs, acc1 16),
// GEMM2 owns 32 out cols (accY 32, b2f 32); no cross-chunk b1f prefetch.
// Peak live ~110 regs < 128 cap of launch_bounds(512,4) -> no spill at
// 16 waves/CU (2x R3). Hs double-buffered again (69632B LDS, 2 blocks/CU),
// ONE barrier per chunk (R3-proven sync structure).

#define N_ATOMS 65536
#define D_IN 256
#define D_HID 1024
#define D_OUT 256
#define TPS 1024   // max 64-row tiles per species (worst case: all rows one species)

typedef __attribute__((ext_vector_type(8))) short short8;
typedef __attribute__((ext_vector_type(4))) short short4v;
typedef __attribute__((ext_vector_type(4))) float float4e;

// ws layout (bytes):
//   [0, 256)           cnt[4] padded: cnt[s] at int offset s*16 (64B apart)
//   [256, 1048832)     bucket[4][65536] int
//   [1048832, 3145984) W1 swizzled bf16 fragments (4*256*1024)
//   [3145984, 5243136) W2 swizzled bf16 fragments (4*1024*256)
#define WS_BUCKET_OFF 256
#define WS_W1_OFF 1048832
#define WS_W2_OFF 3145984

__device__ __forceinline__ short f2bf(float f) {
  unsigned u = __builtin_bit_cast(unsigned, f);
  unsigned r = (u + 0x7FFFu + ((u >> 16) & 1u)) >> 16;   // round-to-nearest-even
  return (short)r;
}

// Swizzle W1/W2 fp32 -> bf16 MFMA B-fragment order; zero padded counters.
// B-frag (16x16x32): lane l holds B[k0 + 8*(l>>4) + j][nt*16 + (l&15)], j=0..7.
// (Used as the A operand in the swapped fused kernel: identical register
// content, interpreted as A[m = l&15][k] = W^T fragment.)
__global__ void prep_kernel(const float* __restrict__ W1, const float* __restrict__ W2,
                            short* __restrict__ w1sw, short* __restrict__ w2sw,
                            int* __restrict__ cnt) {
  int gid = blockIdx.x * 256 + threadIdx.x;   // 262144 threads
  if (gid < 64) cnt[gid] = 0;
  int lane = gid & 63;
  int lr = lane & 15;
  int lk = (lane >> 4) * 8;
  if (gid < 131072) {            // W1: [4][256][1024], NT=64, KS=8
    int ks = (gid >> 6) & 7;
    int nt = (gid >> 9) & 63;
    int s  = gid >> 15;
    const float* src = W1 + ((size_t)(s * 256 + ks * 32 + lk)) * 1024 + nt * 16 + lr;
    short8 v;
    for (int j = 0; j < 8; ++j) v[j] = f2bf(src[(size_t)j * 1024]);
    *(short8*)(w1sw + (size_t)gid * 8) = v;
  } else {                       // W2: [4][1024][256], NT=16, KS=32
    int g = gid - 131072;
    int kt = (g >> 6) & 31;
    int nt = (g >> 11) & 15;
    int s  = g >> 15;
    const float* src = W2 + ((size_t)(s * 1024 + kt * 32 + lk)) * 256 + nt * 16 + lr;
    short8 v;
    for (int j = 0; j < 8; ++j) v[j] = f2bf(src[(size_t)j * 256]);
    *(short8*)(w2sw + (size_t)g * 8) = v;
  }
}

// Bucket rows by species. 32 blocks x 2048 rows. Two-pass block-internal
// histogram; ONE atomicAdd per species per block; then scatter.
#define CF_BLOCKS 32
#define CF_ITERS 8
__global__ void count_fill_kernel(const int* __restrict__ species,
                                  int* __restrict__ cnt, int* __restrict__ bucket) {
  int tid = threadIdx.x;
  int lane = tid & 63, wid = tid >> 6;
  __shared__ int wcnt[CF_ITERS][4][4];   // [iter][wave][species]
  __shared__ int wb[CF_ITERS][4][4];     // exclusive prefix within block
  __shared__ int base_sm[4];
  int sv[CF_ITERS], rk[CF_ITERS];
  unsigned long long below = (1ull << lane) - 1ull;
  int base_i = blockIdx.x * (CF_ITERS * 256);
  #pragma unroll
  for (int it = 0; it < CF_ITERS; ++it) {
    int s = species[base_i + it * 256 + tid] & 3;
    sv[it] = s;
    unsigned long long m0 = __ballot(s == 0);
    unsigned long long m1 = __ballot(s == 1);
    unsigned long long m2 = __ballot(s == 2);
    unsigned long long m3 = __ballot(s == 3);
    unsigned long long ms = (s == 0) ? m0 : (s == 1) ? m1 : (s == 2) ? m2 : m3;
    rk[it] = __popcll(ms & below);
    if (lane == 0) {
      wcnt[it][wid][0] = __popcll(m0);
      wcnt[it][wid][1] = __popcll(m1);
      wcnt[it][wid][2] = __popcll(m2);
      wcnt[it][wid][3] = __popcll(m3);
    }
  }
  __syncthreads();
  if (tid < 4) {
    int ss = tid, run = 0;
    for (int it = 0; it < CF_ITERS; ++it)
      for (int w = 0; w < 4; ++w) {
        wb[it][w][ss] = run;
        run += wcnt[it][w][ss];
      }
    base_sm[ss] = atomicAdd(&cnt[ss * 16], run);
  }
  __syncthreads();
  #pragma unroll
  for (int it = 0; it < CF_ITERS; ++it) {
    int ss = sv[it];
    bucket[ss * N_ATOMS + base_sm[ss] + wb[it][wid][ss] + rk[it]] = base_i + it * 256 + tid;
  }
}

// Fused per-tile MLP, swapped-operand form, 8 waves per block (512 threads),
// tile = 64 rows. Per hid-chunk c (8 chunks of 128):
//   wave w: GEMM1 computes H^T slice [16 hid x 64 rows] (hid = c*128+w*16),
//   silu -> Hs[c&1]; barrier; GEMM2: accY[2][4] += W2^T slice @ H^T
//   (out cols w*32..w*32+31, all 64 rows).
// LDS: Xs 64x264 (33792B) + Hs[2] 64x140 (35840B) = 69632B -> 2 blocks/CU,
// 16 waves/CU. Peak live regs ~110 < 128 cap -> no spill.
#define XS_STRIDE 264
#define HS_STRIDE 140
__global__ __launch_bounds__(512, 4) void fused_kernel(
    const float* __restrict__ x, const int* __restrict__ cntArr,
    const int* __restrict__ bucket, const short* __restrict__ w1sw,
    const short* __restrict__ w2sw, const float* __restrict__ b1,
    const float* __restrict__ b2, float* __restrict__ out) {
  int bid = blockIdx.x;
  // XCD swizzle: bid%8 round-robins XCDs; give species s to XCD pair {2s,2s+1}
  // so each XCD L2 only holds ~1MB of weight fragments.
  int s = (bid & 7) >> 1;
  int t = ((bid >> 3) << 1) | (bid & 1);
  int cnt = cntArr[s * 16];
  int r0 = t * 64;
  if (r0 >= cnt) return;
  int nrows = min(64, cnt - r0);
  const int* buck = bucket + s * N_ATOMS + r0;

  __shared__ short Xs[64 * XS_STRIDE];      // 33792 B
  __shared__ short Hs[2][64 * HS_STRIDE];   // 35840 B

  int tid = threadIdx.x;

  // Stage gathered x tile -> bf16 LDS. 2048 8-elem groups / 512 threads.
  for (int i = 0; i < 4; ++i) {
    int id = tid + i * 512;
    int r = id >> 5;          // row 0..63
    int g = id & 31;          // 8-float group
    short8 v = {};
    if (r < nrows) {
      const float4* src = (const float4*)(x + (size_t)buck[r] * D_IN + g * 8);
      float4 f0 = src[0];
      float4 f1 = src[1];
      v[0] = f2bf(f0.x); v[1] = f2bf(f0.y); v[2] = f2bf(f0.z); v[3] = f2bf(f0.w);
      v[4] = f2bf(f1.x); v[5] = f2bf(f1.y); v[6] = f2bf(f1.z); v[7] = f2bf(f1.w);
    }
    *(short8*)(Xs + r * XS_STRIDE + g * 8) = v;
  }

  int lane = tid & 63;
  int wid = tid >> 6;          // 0..7
  int lr = lane & 15;          // row within 16-tile (X-row in swapped form)
  int lk = (lane >> 4) * 8;    // k base within 32-kstep
  int lq = (lane >> 4) * 4;    // hid/out base within 16-tile

  // Row gather indices for the epilogue (per bt tile).
  int rowIdx[4];
  #pragma unroll
  for (int bt = 0; bt < 4; ++bt) {
    int r = bt * 16 + lr;
    rowIdx[bt] = (r < nrows) ? buck[r] : -1;
  }

  // accY init = b2 bias (folded). Wave covers out cols [wid*32, wid*32+32).
  float4e accY[2][4];
  #pragma unroll
  for (int at = 0; at < 2; ++at) {
    float4e bv = *(const float4e*)(b2 + s * D_OUT + wid * 32 + at * 16 + lq);
    #pragma unroll
    for (int bt = 0; bt < 4; ++bt) accY[at][bt] = bv;
  }

  __syncthreads();   // Xs ready

  for (int c = 0; c < 8; ++c) {
    // ---- load this chunk's W1 fragments (wave's 16-hid slice: nt = c*8+wid) ----
    short8 b1f[8];
    #pragma unroll
    for (int ks = 0; ks < 8; ++ks) {
      int nt = c * 8 + wid;
      b1f[ks] = *(const short8*)(w1sw + ((size_t)((s * 64 + nt) * 8 + ks)) * 512 + lane * 8);
    }
    // acc1 init = b1 bias for this wave's hid slice.
    float4e acc1[4];
    {
      float4e bv = *(const float4e*)(b1 + s * D_HID + c * 128 + wid * 16 + lq);
      #pragma unroll
      for (int bt = 0; bt < 4; ++bt) acc1[bt] = bv;
    }
    // ---- GEMM1: H^T slice [16 hid x 64 rows] = W1^T @ X^T ----
    #pragma unroll
    for (int ks = 0; ks < 8; ++ks) {
      short8 xb[4];
      #pragma unroll
      for (int bt = 0; bt < 4; ++bt)
        xb[bt] = *(const short8*)(Xs + (bt * 16 + lr) * XS_STRIDE + ks * 32 + lk);
      #pragma unroll
      for (int bt = 0; bt < 4; ++bt)
        acc1[bt] = __builtin_amdgcn_mfma_f32_16x16x32_bf16(b1f[ks], xb[bt], acc1[bt], 0, 0, 0);
    }
    // ---- prefetch GEMM2 W2-fragments (hide L2 latency under silu) ----
    // Wave covers out-tiles nt_out = wid*2 + at, kt = c*4 + ks.
    short8 b2f[8];
    #pragma unroll
    for (int ks = 0; ks < 4; ++ks)
      #pragma unroll
      for (int at = 0; at < 2; ++at) {
        int nt = wid * 2 + at;
        int kt = c * 4 + ks;
        b2f[ks * 2 + at] = *(const short8*)(w2sw + ((size_t)((s * 16 + nt) * 32 + kt)) * 512 + lane * 8);
      }
    // ---- silu -> Hs[c&1] (packed b64: 4 consecutive hid per lane) ----
    short* hsb = Hs[c & 1];
    {
      int hidloc = wid * 16 + lq;
      #pragma unroll
      for (int bt = 0; bt < 4; ++bt) {
        float4e v4 = acc1[bt];
        short4v h;
        #pragma unroll
        for (int q = 0; q < 4; ++q) {
          float pre = v4[q];
          float val = pre * __builtin_amdgcn_rcpf(1.0f + __expf(-pre));  // silu
          h[q] = f2bf(val);
        }
        *(short4v*)(hsb + (bt * 16 + lr) * HS_STRIDE + hidloc) = h;
      }
    }
    __syncthreads();   // Hs[c&1] visible; double-buffer isolates next chunk's writes
    // ---- GEMM2 partial: Y^T[out 32 x rows 64] += W2^T @ H^T ----
    #pragma unroll
    for (int ks = 0; ks < 4; ++ks) {
      short8 hb[4];
      #pragma unroll
      for (int bt = 0; bt < 4; ++bt)
        hb[bt] = *(const short8*)(hsb + (bt * 16 + lr) * HS_STRIDE + ks * 32 + lk);
      #pragma unroll
      for (int at = 0; at < 2; ++at)
        #pragma unroll
        for (int bt = 0; bt < 4; ++bt)
          accY[at][bt] = __builtin_amdgcn_mfma_f32_16x16x32_bf16(b2f[ks * 2 + at], hb[bt], accY[at][bt], 0, 0, 0);
    }
  }

  // ---- epilogue: scatter Y rows, 16B per lane (bias already folded in) ----
  #pragma unroll
  for (int at = 0; at < 2; ++at) {
    int nb = wid * 32 + at * 16 + lq;
    #pragma unroll
    for (int bt = 0; bt < 4; ++bt) {
      if (rowIdx[bt] >= 0)
        *(float4e*)(out + (size_t)rowIdx[bt] * D_OUT + nb) = accY[at][bt];
    }
  }
}

extern "C" void kernel_launch(void* const* d_in, const int* in_sizes, int n_in,
                              void* d_out, int out_size, void* d_ws, size_t ws_size,
                              hipStream_t stream) {
  const float* x  = (const float*)d_in[0];
  const int* spc  = (const int*)d_in[1];
  const float* W1 = (const float*)d_in[2];
  const float* b1 = (const float*)d_in[3];
  const float* W2 = (const float*)d_in[4];
  const float* b2 = (const float*)d_in[5];
  float* out = (float*)d_out;

  int*   cnt    = (int*)d_ws;
  int*   bucket = (int*)((char*)d_ws + WS_BUCKET_OFF);
  short* w1sw   = (short*)((char*)d_ws + WS_W1_OFF);
  short* w2sw   = (short*)((char*)d_ws + WS_W2_OFF);

  prep_kernel<<<1024, 256, 0, stream>>>(W1, W2, w1sw, w2sw, cnt);
  count_fill_kernel<<<CF_BLOCKS, 256, 0, stream>>>(spc, cnt, bucket);
  fused_kernel<<<4 * TPS, 512, 0, stream>>>(x, cnt, bucket, w1sw, w2sw, b1, b2, out);
}

// Round 5
// 270.666 us; speedup vs baseline: 1.5582x; 1.1673x over previous
//
#include <hip/hip_runtime.h>
#include <hip/hip_bf16.h>

// CentralSpecificModel: per-species 2-layer MLP (256 -> 1024 -> 256), 4 species,
// N=65536 rows, fp32 in/out. Bucket rows by species; fused per-64-row-tile
// kernel does GEMM1+silu+GEMM2 with bf16 MFMA (16x16x32), swapped operands
// (weights as A, X/H as B -> H^T/Y^T, packed Hs writes, float4 epilogue).
// R7: serial-pipe-sum model: MFMA 33 + LDS 31 + L2 29 + VALU 27 ~= 120us ~=
// R3's 129us measured (R6's thin-wave split doubled LDS -> 222us, confirming).
// Shrink the serial sum, keep R3's proven 4-wave/64-row shape:
//  (a) chunk 128->256 hid (4 chunks): X LDS re-reads 8->4 passes (31->23us),
//      Hs single-buffered 64x264 (two-barrier deferred-write, R5-proven-correct);
//      LDS 67584B -> 2 blocks/CU. Regs ~200 < 256 cap of launch_bounds(256,2)
//      (R5's spills came from a ~170 cap, not this structure).
//  (b) v_cvt_pk_bf16_f32 inline asm replaces f2bf in silu + staging
//      (2 floats/instr vs ~4 instr/float: VALU 27->~15us).
//  (c) W-frag loads inside unrolled ks loops -> compiler hoists, overlaps L2
//      latency with MFMA.

#define N_ATOMS 65536
#define D_IN 256
#define D_HID 1024
#define D_OUT 256
#define TPS 1024   // max 64-row tiles per species (worst case: all rows one species)

typedef __attribute__((ext_vector_type(8))) short short8;
typedef __attribute__((ext_vector_type(4))) float float4e;
typedef __attribute__((ext_vector_type(2))) unsigned uint2e;
typedef __attribute__((ext_vector_type(4))) unsigned uint4e;

// ws layout (bytes):
//   [0, 256)           cnt[4] padded: cnt[s] at int offset s*16 (64B apart)
//   [256, 1048832)     bucket[4][65536] int
//   [1048832, 3145984) W1 swizzled bf16 fragments (4*256*1024)
//   [3145984, 5243136) W2 swizzled bf16 fragments (4*1024*256)
#define WS_BUCKET_OFF 256
#define WS_W1_OFF 1048832
#define WS_W2_OFF 3145984

__device__ __forceinline__ short f2bf(float f) {
  unsigned u = __builtin_bit_cast(unsigned, f);
  unsigned r = (u + 0x7FFFu + ((u >> 16) & 1u)) >> 16;   // round-to-nearest-even
  return (short)r;
}

// Two f32 -> packed 2x bf16 in one instruction (low half = a, high half = b).
__device__ __forceinline__ unsigned cvt_pk_bf16(float a, float b) {
  unsigned r;
  asm("v_cvt_pk_bf16_f32 %0, %1, %2" : "=v"(r) : "v"(a), "v"(b));
  return r;
}

// Swizzle W1/W2 fp32 -> bf16 MFMA B-fragment order; zero padded counters.
// B-frag (16x16x32): lane l holds B[k0 + 8*(l>>4) + j][nt*16 + (l&15)], j=0..7.
// (Used as the A operand in the swapped fused kernel: identical register
// content, interpreted as A[m = l&15][k] = W^T fragment.)
__global__ void prep_kernel(const float* __restrict__ W1, const float* __restrict__ W2,
                            short* __restrict__ w1sw, short* __restrict__ w2sw,
                            int* __restrict__ cnt) {
  int gid = blockIdx.x * 256 + threadIdx.x;   // 262144 threads
  if (gid < 64) cnt[gid] = 0;
  int lane = gid & 63;
  int lr = lane & 15;
  int lk = (lane >> 4) * 8;
  if (gid < 131072) {            // W1: [4][256][1024], NT=64, KS=8
    int ks = (gid >> 6) & 7;
    int nt = (gid >> 9) & 63;
    int s  = gid >> 15;
    const float* src = W1 + ((size_t)(s * 256 + ks * 32 + lk)) * 1024 + nt * 16 + lr;
    short8 v;
    for (int j = 0; j < 8; ++j) v[j] = f2bf(src[(size_t)j * 1024]);
    *(short8*)(w1sw + (size_t)gid * 8) = v;
  } else {                       // W2: [4][1024][256], NT=16, KS=32
    int g = gid - 131072;
    int kt = (g >> 6) & 31;
    int nt = (g >> 11) & 15;
    int s  = g >> 15;
    const float* src = W2 + ((size_t)(s * 1024 + kt * 32 + lk)) * 256 + nt * 16 + lr;
    short8 v;
    for (int j = 0; j < 8; ++j) v[j] = f2bf(src[(size_t)j * 256]);
    *(short8*)(w2sw + (size_t)g * 8) = v;
  }
}

// Bucket rows by species. 32 blocks x 2048 rows. Two-pass block-internal
// histogram; ONE atomicAdd per species per block; then scatter.
#define CF_BLOCKS 32
#define CF_ITERS 8
__global__ void count_fill_kernel(const int* __restrict__ species,
                                  int* __restrict__ cnt, int* __restrict__ bucket) {
  int tid = threadIdx.x;
  int lane = tid & 63, wid = tid >> 6;
  __shared__ int wcnt[CF_ITERS][4][4];   // [iter][wave][species]
  __shared__ int wb[CF_ITERS][4][4];     // exclusive prefix within block
  __shared__ int base_sm[4];
  int sv[CF_ITERS], rk[CF_ITERS];
  unsigned long long below = (1ull << lane) - 1ull;
  int base_i = blockIdx.x * (CF_ITERS * 256);
  #pragma unroll
  for (int it = 0; it < CF_ITERS; ++it) {
    int s = species[base_i + it * 256 + tid] & 3;
    sv[it] = s;
    unsigned long long m0 = __ballot(s == 0);
    unsigned long long m1 = __ballot(s == 1);
    unsigned long long m2 = __ballot(s == 2);
    unsigned long long m3 = __ballot(s == 3);
    unsigned long long ms = (s == 0) ? m0 : (s == 1) ? m1 : (s == 2) ? m2 : m3;
    rk[it] = __popcll(ms & below);
    if (lane == 0) {
      wcnt[it][wid][0] = __popcll(m0);
      wcnt[it][wid][1] = __popcll(m1);
      wcnt[it][wid][2] = __popcll(m2);
      wcnt[it][wid][3] = __popcll(m3);
    }
  }
  __syncthreads();
  if (tid < 4) {
    int ss = tid, run = 0;
    for (int it = 0; it < CF_ITERS; ++it)
      for (int w = 0; w < 4; ++w) {
        wb[it][w][ss] = run;
        run += wcnt[it][w][ss];
      }
    base_sm[ss] = atomicAdd(&cnt[ss * 16], run);
  }
  __syncthreads();
  #pragma unroll
  for (int it = 0; it < CF_ITERS; ++it) {
    int ss = sv[it];
    bucket[ss * N_ATOMS + base_sm[ss] + wb[it][wid][ss] + rk[it]] = base_i + it * 256 + tid;
  }
}

// Fused per-tile MLP, swapped-operand form. Block = 256 threads (4 waves),
// tile = 64 rows, hid chunk = 256 (4 chunks). Per chunk c:
//   GEMM1: H^T chunk [256 hid x 64 rows] = W1^T @ X^T (wave owns 64 hid cols);
//   silu -> regs; barrier (prior GEMM2 readers done); Hs writes (uint2 packed);
//   barrier; GEMM2: accY += W2^T[.., k-slice c] @ H^T (wave owns 64 out cols).
// LDS: Xs 64x264 + Hs 64x264 = 67584B -> 2 blocks/CU. Peak regs ~200 < 256 cap.
#define XS_STRIDE 264
#define HS_STRIDE 264
__global__ __launch_bounds__(256, 2) void fused_kernel(
    const float* __restrict__ x, const int* __restrict__ cntArr,
    const int* __restrict__ bucket, const short* __restrict__ w1sw,
    const short* __restrict__ w2sw, const float* __restrict__ b1,
    const float* __restrict__ b2, float* __restrict__ out) {
  int bid = blockIdx.x;
  // XCD swizzle: bid%8 round-robins XCDs; give species s to XCD pair {2s,2s+1}
  // so each XCD L2 only holds ~1MB of weight fragments.
  int s = (bid & 7) >> 1;
  int t = ((bid >> 3) << 1) | (bid & 1);
  int cnt = cntArr[s * 16];
  int r0 = t * 64;
  if (r0 >= cnt) return;
  int nrows = min(64, cnt - r0);
  const int* buck = bucket + s * N_ATOMS + r0;

  __shared__ short Xs[64 * XS_STRIDE];   // 33792 B
  __shared__ short Hs[64 * HS_STRIDE];   // 33792 B

  int tid = threadIdx.x;

  // Stage gathered x tile -> bf16 LDS (cvt_pk packed). 2048 8-elem groups.
  for (int i = 0; i < 8; ++i) {
    int id = tid + i * 256;
    int r = id >> 5;          // row 0..63
    int g = id & 31;          // 8-float group
    float4 f0 = {}, f1 = {};
    if (r < nrows) {
      const float4* src = (const float4*)(x + (size_t)buck[r] * D_IN + g * 8);
      f0 = src[0];
      f1 = src[1];
    }
    uint4e v;
    v.x = cvt_pk_bf16(f0.x, f0.y);
    v.y = cvt_pk_bf16(f0.z, f0.w);
    v.z = cvt_pk_bf16(f1.x, f1.y);
    v.w = cvt_pk_bf16(f1.z, f1.w);
    *(uint4e*)(Xs + r * XS_STRIDE + g * 8) = v;
  }

  int lane = tid & 63;
  int wid = tid >> 6;
  int lr = lane & 15;          // row within 16-tile (X-row in swapped form)
  int lk = (lane >> 4) * 8;    // k base within 32-kstep
  int lq = (lane >> 4) * 4;    // hid/out base within 16-tile

  // Row gather indices for the epilogue (per bt tile).
  int rowIdx[4];
  #pragma unroll
  for (int bt = 0; bt < 4; ++bt) {
    int r = bt * 16 + lr;
    rowIdx[bt] = (r < nrows) ? buck[r] : -1;
  }

  // accY init = b2 bias (folded). Wave covers out cols [wid*64, wid*64+64).
  float4e accY[4][4];
  #pragma unroll
  for (int at = 0; at < 4; ++at) {
    float4e bv = *(const float4e*)(b2 + s * D_OUT + wid * 64 + at * 16 + lq);
    #pragma unroll
    for (int bt = 0; bt < 4; ++bt) accY[at][bt] = bv;
  }

  __syncthreads();   // Xs ready

  for (int c = 0; c < 4; ++c) {
    // acc1 init = b1 bias; wave owns hid cols c*256 + [wid*64, wid*64+64).
    float4e acc1[4][4];
    #pragma unroll
    for (int at = 0; at < 4; ++at) {
      float4e bv = *(const float4e*)(b1 + s * D_HID + c * 256 + wid * 64 + at * 16 + lq);
      #pragma unroll
      for (int bt = 0; bt < 4; ++bt) acc1[at][bt] = bv;
    }
    // ---- GEMM1: H^T chunk [256 hid x 64 rows] = W1^T @ X^T, full K=256 ----
    #pragma unroll
    for (int ks = 0; ks < 8; ++ks) {
      short8 xb[4];
      #pragma unroll
      for (int bt = 0; bt < 4; ++bt)
        xb[bt] = *(const short8*)(Xs + (bt * 16 + lr) * XS_STRIDE + ks * 32 + lk);
      short8 b1f[4];
      #pragma unroll
      for (int at = 0; at < 4; ++at) {
        int nt = c * 16 + wid * 4 + at;
        b1f[at] = *(const short8*)(w1sw + ((size_t)((s * 64 + nt) * 8 + ks)) * 512 + lane * 8);
      }
      #pragma unroll
      for (int at = 0; at < 4; ++at)
        #pragma unroll
        for (int bt = 0; bt < 4; ++bt)
          acc1[at][bt] = __builtin_amdgcn_mfma_f32_16x16x32_bf16(b1f[at], xb[bt], acc1[at][bt], 0, 0, 0);
    }
    // ---- silu -> registers (packed bf16 pairs via v_cvt_pk_bf16_f32) ----
    uint2e hreg[4][4];
    #pragma unroll
    for (int at = 0; at < 4; ++at)
      #pragma unroll
      for (int bt = 0; bt < 4; ++bt) {
        float4e v4 = acc1[at][bt];
        float sv[4];
        #pragma unroll
        for (int q = 0; q < 4; ++q) {
          float pre = v4[q];
          sv[q] = pre * __builtin_amdgcn_rcpf(1.0f + __expf(-pre));  // silu
        }
        hreg[at][bt].x = cvt_pk_bf16(sv[0], sv[1]);
        hreg[at][bt].y = cvt_pk_bf16(sv[2], sv[3]);
      }
    __syncthreads();   // all waves' GEMM2 reads of previous chunk's Hs are done
    // ---- Hs writes (8B packed: 4 consecutive hid per lane) ----
    #pragma unroll
    for (int at = 0; at < 4; ++at) {
      int hidloc = wid * 64 + at * 16 + lq;
      #pragma unroll
      for (int bt = 0; bt < 4; ++bt)
        *(uint2e*)(Hs + (bt * 16 + lr) * HS_STRIDE + hidloc) = hreg[at][bt];
    }
    __syncthreads();   // Hs chunk c visible to all waves
    // ---- GEMM2 partial: Y^T += W2^T[k-slice c] @ H^T ----
    #pragma unroll
    for (int ks = 0; ks < 8; ++ks) {
      short8 hb[4];
      #pragma unroll
      for (int bt = 0; bt < 4; ++bt)
        hb[bt] = *(const short8*)(Hs + (bt * 16 + lr) * HS_STRIDE + ks * 32 + lk);
      short8 b2f[4];
      #pragma unroll
      for (int at = 0; at < 4; ++at) {
        int nt = wid * 4 + at;
        int kt = c * 8 + ks;
        b2f[at] = *(const short8*)(w2sw + ((size_t)((s * 16 + nt) * 32 + kt)) * 512 + lane * 8);
      }
      #pragma unroll
      for (int at = 0; at < 4; ++at)
        #pragma unroll
        for (int bt = 0; bt < 4; ++bt)
          accY[at][bt] = __builtin_amdgcn_mfma_f32_16x16x32_bf16(b2f[at], hb[bt], accY[at][bt], 0, 0, 0);
    }
  }

  // ---- epilogue: scatter Y rows, 16B per lane (bias already folded in) ----
  #pragma unroll
  for (int at = 0; at < 4; ++at) {
    int nb = wid * 64 + at * 16 + lq;
    #pragma unroll
    for (int bt = 0; bt < 4; ++bt) {
      if (rowIdx[bt] >= 0)
        *(float4e*)(out + (size_t)rowIdx[bt] * D_OUT + nb) = accY[at][bt];
    }
  }
}

extern "C" void kernel_launch(void* const* d_in, const int* in_sizes, int n_in,
                              void* d_out, int out_size, void* d_ws, size_t ws_size,
                              hipStream_t stream) {
  const float* x  = (const float*)d_in[0];
  const int* spc  = (const int*)d_in[1];
  const float* W1 = (const float*)d_in[2];
  const float* b1 = (const float*)d_in[3];
  const float* W2 = (const float*)d_in[4];
  const float* b2 = (const float*)d_in[5];
  float* out = (float*)d_out;

  int*   cnt    = (int*)d_ws;
  int*   bucket = (int*)((char*)d_ws + WS_BUCKET_OFF);
  short* w1sw   = (short*)((char*)d_ws + WS_W1_OFF);
  short* w2sw   = (short*)((char*)d_ws + WS_W2_OFF);

  prep_kernel<<<1024, 256, 0, stream>>>(W1, W2, w1sw, w2sw, cnt);
  count_fill_kernel<<<CF_BLOCKS, 256, 0, stream>>>(spc, cnt, bucket);
  fused_kernel<<<4 * TPS, 256, 0, stream>>>(x, cnt, bucket, w1sw, w2sw, b1, b2, out);
}

// Round 6
// 219.871 us; speedup vs baseline: 1.9182x; 1.2310x over previous
//
#include <hip/hip_runtime.h>
#include <hip/hip_bf16.h>

// CentralSpecificModel: per-species 2-layer MLP (256 -> 1024 -> 256), 4 species,
// N=65536 rows, fp32 in/out. Bucket rows by species; fused per-64-row-tile
// kernel does GEMM1+silu+GEMM2 with bf16 MFMA (16x16x32), swapped operands
// (weights as A, X/H as B -> H^T/Y^T), batched B-frag prefetch, dbuf Hs.
// R8: REVERT to the proven R3 structure (129us fused; R5 spilled via reg-cap,
// R6 doubled X LDS reads via wave hid-split, R7 serialized weight loads by
// dropping batched prefetch). Only in-place deltas:
//  (a) v_cvt_pk_bf16_f32 packed conversion in silu output + X staging
//      (R7-proven correct; VALUBusy 21->13 there).
//  (b) s_setprio(1) around MFMA clusters: the 2 resident blocks/CU are not
//      co-barriered -> cross-block phase diversity (attn-like regime, not
//      m190's lockstep GEMM).
// Everything else byte-identical to R3: strides 280/152, Hs[2] dbuf, ONE
// barrier per chunk, 16-frag batched prefetch, b1f(c+1) prefetch under GEMM2.

#define N_ATOMS 65536
#define D_IN 256
#define D_HID 1024
#define D_OUT 256
#define TPS 1024   // max 64-row tiles per species (worst case: all rows one species)

typedef __attribute__((ext_vector_type(8))) short short8;
typedef __attribute__((ext_vector_type(4))) short short4v;
typedef __attribute__((ext_vector_type(4))) float float4e;
typedef __attribute__((ext_vector_type(2))) unsigned uint2e;
typedef __attribute__((ext_vector_type(4))) unsigned uint4e;

// ws layout (bytes):
//   [0, 256)           cnt[4] padded: cnt[s] at int offset s*16 (64B apart)
//   [256, 1048832)     bucket[4][65536] int
//   [1048832, 3145984) W1 swizzled bf16 fragments (4*256*1024)
//   [3145984, 5243136) W2 swizzled bf16 fragments (4*1024*256)
#define WS_BUCKET_OFF 256
#define WS_W1_OFF 1048832
#define WS_W2_OFF 3145984

__device__ __forceinline__ short f2bf(float f) {
  unsigned u = __builtin_bit_cast(unsigned, f);
  unsigned r = (u + 0x7FFFu + ((u >> 16) & 1u)) >> 16;   // round-to-nearest-even
  return (short)r;
}

// Two f32 -> packed 2x bf16 in one instruction (low half = a, high half = b).
__device__ __forceinline__ unsigned cvt_pk_bf16(float a, float b) {
  unsigned r;
  asm("v_cvt_pk_bf16_f32 %0, %1, %2" : "=v"(r) : "v"(a), "v"(b));
  return r;
}

// Swizzle W1/W2 fp32 -> bf16 MFMA B-fragment order; zero padded counters.
// B-frag (16x16x32): lane l holds B[k0 + 8*(l>>4) + j][nt*16 + (l&15)], j=0..7.
// (Used as the A operand in the swapped fused kernel.)
__global__ void prep_kernel(const float* __restrict__ W1, const float* __restrict__ W2,
                            short* __restrict__ w1sw, short* __restrict__ w2sw,
                            int* __restrict__ cnt) {
  int gid = blockIdx.x * 256 + threadIdx.x;   // 262144 threads
  if (gid < 64) cnt[gid] = 0;
  int lane = gid & 63;
  int lr = lane & 15;
  int lk = (lane >> 4) * 8;
  if (gid < 131072) {            // W1: [4][256][1024], NT=64, KS=8
    int ks = (gid >> 6) & 7;
    int nt = (gid >> 9) & 63;
    int s  = gid >> 15;
    const float* src = W1 + ((size_t)(s * 256 + ks * 32 + lk)) * 1024 + nt * 16 + lr;
    short8 v;
    for (int j = 0; j < 8; ++j) v[j] = f2bf(src[(size_t)j * 1024]);
    *(short8*)(w1sw + (size_t)gid * 8) = v;
  } else {                       // W2: [4][1024][256], NT=16, KS=32
    int g = gid - 131072;
    int kt = (g >> 6) & 31;
    int nt = (g >> 11) & 15;
    int s  = g >> 15;
    const float* src = W2 + ((size_t)(s * 1024 + kt * 32 + lk)) * 256 + nt * 16 + lr;
    short8 v;
    for (int j = 0; j < 8; ++j) v[j] = f2bf(src[(size_t)j * 256]);
    *(short8*)(w2sw + (size_t)g * 8) = v;
  }
}

// Bucket rows by species. 32 blocks x 2048 rows. Two-pass block-internal
// histogram; ONE atomicAdd per species per block; then scatter.
#define CF_BLOCKS 32
#define CF_ITERS 8
__global__ void count_fill_kernel(const int* __restrict__ species,
                                  int* __restrict__ cnt, int* __restrict__ bucket) {
  int tid = threadIdx.x;
  int lane = tid & 63, wid = tid >> 6;
  __shared__ int wcnt[CF_ITERS][4][4];   // [iter][wave][species]
  __shared__ int wb[CF_ITERS][4][4];     // exclusive prefix within block
  __shared__ int base_sm[4];
  int sv[CF_ITERS], rk[CF_ITERS];
  unsigned long long below = (1ull << lane) - 1ull;
  int base_i = blockIdx.x * (CF_ITERS * 256);
  #pragma unroll
  for (int it = 0; it < CF_ITERS; ++it) {
    int s = species[base_i + it * 256 + tid] & 3;
    sv[it] = s;
    unsigned long long m0 = __ballot(s == 0);
    unsigned long long m1 = __ballot(s == 1);
    unsigned long long m2 = __ballot(s == 2);
    unsigned long long m3 = __ballot(s == 3);
    unsigned long long ms = (s == 0) ? m0 : (s == 1) ? m1 : (s == 2) ? m2 : m3;
    rk[it] = __popcll(ms & below);
    if (lane == 0) {
      wcnt[it][wid][0] = __popcll(m0);
      wcnt[it][wid][1] = __popcll(m1);
      wcnt[it][wid][2] = __popcll(m2);
      wcnt[it][wid][3] = __popcll(m3);
    }
  }
  __syncthreads();
  if (tid < 4) {
    int ss = tid, run = 0;
    for (int it = 0; it < CF_ITERS; ++it)
      for (int w = 0; w < 4; ++w) {
        wb[it][w][ss] = run;
        run += wcnt[it][w][ss];
      }
    base_sm[ss] = atomicAdd(&cnt[ss * 16], run);
  }
  __syncthreads();
  #pragma unroll
  for (int it = 0; it < CF_ITERS; ++it) {
    int ss = sv[it];
    bucket[ss * N_ATOMS + base_sm[ss] + wb[it][wid][ss] + rk[it]] = base_i + it * 256 + tid;
  }
}

// Fused per-tile MLP, swapped-operand form. Block = 256 threads (4 waves),
// tile = 64 rows. GEMM1: H^T = W1^T @ X^T, lane holds 4 consecutive hid ->
// packed 8B Hs writes. GEMM2: Y^T = W2^T @ H^T -> float4 epilogue stores.
// LDS: Xs 64x280 (35840B) + Hs[2] 64x152 (38912B) = 74752B -> 2 blocks/CU.
#define XS_STRIDE 280
#define HS_STRIDE 152
__global__ __launch_bounds__(256, 2) void fused_kernel(
    const float* __restrict__ x, const int* __restrict__ cntArr,
    const int* __restrict__ bucket, const short* __restrict__ w1sw,
    const short* __restrict__ w2sw, const float* __restrict__ b1,
    const float* __restrict__ b2, float* __restrict__ out) {
  int bid = blockIdx.x;
  // XCD swizzle: bid%8 round-robins XCDs; give species s to XCD pair {2s,2s+1}
  // so each XCD L2 only holds ~1MB of weight fragments.
  int s = (bid & 7) >> 1;
  int t = ((bid >> 3) << 1) | (bid & 1);
  int cnt = cntArr[s * 16];
  int r0 = t * 64;
  if (r0 >= cnt) return;
  int nrows = min(64, cnt - r0);
  const int* buck = bucket + s * N_ATOMS + r0;

  __shared__ short Xs[64 * XS_STRIDE];
  __shared__ short Hs[2][64 * HS_STRIDE];

  int tid = threadIdx.x;

  // Stage gathered x tile -> bf16 LDS (cvt_pk packed). 2048 8-elem groups.
  for (int i = 0; i < 8; ++i) {
    int id = tid + i * 256;
    int r = id >> 5;          // row 0..63
    int g = id & 31;          // 8-float group
    float4 f0 = {}, f1 = {};
    if (r < nrows) {
      const float4* src = (const float4*)(x + (size_t)buck[r] * D_IN + g * 8);
      f0 = src[0];
      f1 = src[1];
    }
    uint4e v;
    v.x = cvt_pk_bf16(f0.x, f0.y);
    v.y = cvt_pk_bf16(f0.z, f0.w);
    v.z = cvt_pk_bf16(f1.x, f1.y);
    v.w = cvt_pk_bf16(f1.z, f1.w);
    *(uint4e*)(Xs + r * XS_STRIDE + g * 8) = v;
  }

  int lane = tid & 63;
  int wid = tid >> 6;
  int lr = lane & 15;          // row within 16-tile (X-row in swapped form)
  int lk = (lane >> 4) * 8;    // k base within 32-kstep
  int lq = (lane >> 4) * 4;    // hid/out base within 16-tile

  // Row gather indices for the epilogue (per bt tile).
  int rowIdx[4];
  #pragma unroll
  for (int bt = 0; bt < 4; ++bt) {
    int r = bt * 16 + lr;
    rowIdx[bt] = (r < nrows) ? buck[r] : -1;
  }

  // accY init = b2 bias (folded). Wave covers out cols [wid*64, wid*64+64).
  float4e accY[4][4];
  #pragma unroll
  for (int at = 0; at < 4; ++at) {
    float4e bv = *(const float4e*)(b2 + s * D_OUT + wid * 64 + at * 16 + lq);
    #pragma unroll
    for (int bt = 0; bt < 4; ++bt) accY[at][bt] = bv;
  }

  // Preload GEMM1 W1-fragments for c=0 (16 batched loads, one latency exposure).
  short8 b1f[16];
  #pragma unroll
  for (int ks = 0; ks < 8; ++ks)
    #pragma unroll
    for (int at = 0; at < 2; ++at) {
      int nt = 0 * 8 + wid * 2 + at;
      b1f[ks * 2 + at] = *(const short8*)(w1sw + ((size_t)((s * 64 + nt) * 8 + ks)) * 512 + lane * 8);
    }

  __syncthreads();   // Xs ready

  for (int c = 0; c < 8; ++c) {
    // acc1 init = b1 bias for this chunk's hid slice.
    float4e acc1[2][4];
    #pragma unroll
    for (int at = 0; at < 2; ++at) {
      float4e bv = *(const float4e*)(b1 + s * D_HID + c * 128 + wid * 32 + at * 16 + lq);
      #pragma unroll
      for (int bt = 0; bt < 4; ++bt) acc1[at][bt] = bv;
    }
    // ---- GEMM1: H^T chunk [128 hid x 64 rows] = W1^T @ X^T ----
    __builtin_amdgcn_s_setprio(1);
    #pragma unroll
    for (int ks = 0; ks < 8; ++ks) {
      short8 xb[4];
      #pragma unroll
      for (int bt = 0; bt < 4; ++bt)
        xb[bt] = *(const short8*)(Xs + (bt * 16 + lr) * XS_STRIDE + ks * 32 + lk);
      #pragma unroll
      for (int at = 0; at < 2; ++at)
        #pragma unroll
        for (int bt = 0; bt < 4; ++bt)
          acc1[at][bt] = __builtin_amdgcn_mfma_f32_16x16x32_bf16(b1f[ks * 2 + at], xb[bt], acc1[at][bt], 0, 0, 0);
    }
    __builtin_amdgcn_s_setprio(0);
    // ---- prefetch GEMM2 W2-fragments (latency hidden under silu+barrier) ----
    short8 b2f[16];
    #pragma unroll
    for (int ks = 0; ks < 4; ++ks)
      #pragma unroll
      for (int at = 0; at < 4; ++at) {
        int nt = wid * 4 + at;
        int kt = c * 4 + ks;
        b2f[ks * 4 + at] = *(const short8*)(w2sw + ((size_t)((s * 16 + nt) * 32 + kt)) * 512 + lane * 8);
      }
    // ---- silu -> Hs[c&1] (cvt_pk packed, 8B writes: 4 consecutive hid/lane) ----
    short* hsb = Hs[c & 1];
    #pragma unroll
    for (int at = 0; at < 2; ++at) {
      int hidloc = wid * 32 + at * 16 + lq;
      #pragma unroll
      for (int bt = 0; bt < 4; ++bt) {
        float4e v4 = acc1[at][bt];
        float sv0 = v4[0] * __builtin_amdgcn_rcpf(1.0f + __expf(-v4[0]));
        float sv1 = v4[1] * __builtin_amdgcn_rcpf(1.0f + __expf(-v4[1]));
        float sv2 = v4[2] * __builtin_amdgcn_rcpf(1.0f + __expf(-v4[2]));
        float sv3 = v4[3] * __builtin_amdgcn_rcpf(1.0f + __expf(-v4[3]));
        uint2e h;
        h.x = cvt_pk_bf16(sv0, sv1);
        h.y = cvt_pk_bf16(sv2, sv3);
        *(uint2e*)(hsb + (bt * 16 + lr) * HS_STRIDE + hidloc) = h;
      }
    }
    __syncthreads();   // Hs[c&1] visible; prior readers of Hs[(c+1)&1] done
    // ---- prefetch next chunk's W1-fragments (hidden under GEMM2 MFMA) ----
    if (c < 7) {
      #pragma unroll
      for (int ks = 0; ks < 8; ++ks)
        #pragma unroll
        for (int at = 0; at < 2; ++at) {
          int nt = (c + 1) * 8 + wid * 2 + at;
          b1f[ks * 2 + at] = *(const short8*)(w1sw + ((size_t)((s * 64 + nt) * 8 + ks)) * 512 + lane * 8);
        }
    }
    // ---- GEMM2 partial: Y^T += W2^T @ H^T ----
    __builtin_amdgcn_s_setprio(1);
    #pragma unroll
    for (int ks = 0; ks < 4; ++ks) {
      short8 hb[4];
      #pragma unroll
      for (int bt = 0; bt < 4; ++bt)
        hb[bt] = *(const short8*)(hsb + (bt * 16 + lr) * HS_STRIDE + ks * 32 + lk);
      #pragma unroll
      for (int at = 0; at < 4; ++at)
        #pragma unroll
        for (int bt = 0; bt < 4; ++bt)
          accY[at][bt] = __builtin_amdgcn_mfma_f32_16x16x32_bf16(b2f[ks * 4 + at], hb[bt], accY[at][bt], 0, 0, 0);
    }
    __builtin_amdgcn_s_setprio(0);
  }

  // ---- epilogue: scatter Y rows, 16B per lane (bias already folded in) ----
  #pragma unroll
  for (int at = 0; at < 4; ++at) {
    int nb = wid * 64 + at * 16 + lq;
    #pragma unroll
    for (int bt = 0; bt < 4; ++bt) {
      if (rowIdx[bt] >= 0)
        *(float4e*)(out + (size_t)rowIdx[bt] * D_OUT + nb) = accY[at][bt];
    }
  }
}

extern "C" void kernel_launch(void* const* d_in, const int* in_sizes, int n_in,
                              void* d_out, int out_size, void* d_ws, size_t ws_size,
                              hipStream_t stream) {
  const float* x  = (const float*)d_in[0];
  const int* spc  = (const int*)d_in[1];
  const float* W1 = (const float*)d_in[2];
  const float* b1 = (const float*)d_in[3];
  const float* W2 = (const float*)d_in[4];
  const float* b2 = (const float*)d_in[5];
  float* out = (float*)d_out;

  int*   cnt    = (int*)d_ws;
  int*   bucket = (int*)((char*)d_ws + WS_BUCKET_OFF);
  short* w1sw   = (short*)((char*)d_ws + WS_W1_OFF);
  short* w2sw   = (short*)((char*)d_ws + WS_W2_OFF);

  prep_kernel<<<1024, 256, 0, stream>>>(W1, W2, w1sw, w2sw, cnt);
  count_fill_kernel<<<CF_BLOCKS, 256, 0, stream>>>(spc, cnt, bucket);
  fused_kernel<<<4 * TPS, 256, 0, stream>>>(x, cnt, bucket, w1sw, w2sw, b1, b2, out);
}